// Round 1
// baseline (2077.166 us; speedup 1.0000x reference)
//
#include <hip/hip_runtime.h>
#include <cstdint>
#include <cstddef>

#define N_ATOMS 500000
#define NFEAT 9
#define DIM 300
#define NSEG4 75      // DIM/4 float4 per row
#define NT 512
#define BK 20         // K-chunk (divides 300)
#define BKSEG 5       // BK/4
#define BM 64         // atoms per block
#define BN 64         // tokens per chunk

// ---- ws layout ----
// 0       : double loss_part[256]   (2048)
// 2048    : double wnormd[512]      (4096)
// 6144    : float  wnormf[512]      (2048)
// 8192    : int    counters[8]      (32)   [0..3]=counts, [4..7]=cursors
// 8256    : int    order[N_ATOMS]   (2,000,000)
// 2008256 : int    idx[N_ATOMS]     (2,000,000)
#define WS_FAST_NEED 4008256

__device__ __forceinline__ void classRange(int v, int& lo, int& hi) {
  if (v == 5)      { lo = 0;   hi = 377; }
  else if (v == 6) { lo = 378; hi = 433; }
  else if (v == 7) { lo = 434; hi = 488; }
  else             { lo = 489; hi = 511; }
}
__device__ __forceinline__ int classOf(int v) {
  return (v == 5) ? 0 : (v == 6) ? 1 : (v == 7) ? 2 : 3;
}

// K0: token norms (fp64 + fp32), zero loss partials + counters.
__global__ __launch_bounds__(256) void k_prep(const float* __restrict__ w,
    double* __restrict__ wnormd, float* __restrict__ wnormf,
    double* __restrict__ loss_part, int* __restrict__ counters)
{
  const int t = blockIdx.x * 4 + (threadIdx.x >> 6);
  const int lane = threadIdx.x & 63;
  double s = 0.0;
  for (int j = lane; j < DIM; j += 64) {
    const double v = (double)w[(size_t)t * DIM + j];
    s = fma(v, v, s);
  }
  #pragma unroll
  for (int off = 32; off; off >>= 1) s += __shfl_down(s, off);
  if (lane == 0) { wnormd[t] = s; wnormf[t] = (float)s; }
  if (blockIdx.x == 0) {
    loss_part[threadIdx.x] = 0.0;
    if (threadIdx.x < 8) counters[threadIdx.x] = 0;
  }
}

// K1: class histogram (block-aggregated)
__global__ __launch_bounds__(256) void k_count(const int* __restrict__ x,
                                               int* __restrict__ counters)
{
  __shared__ int c[4];
  if (threadIdx.x < 4) c[threadIdx.x] = 0;
  __syncthreads();
  const int a = blockIdx.x * 256 + threadIdx.x;
  if (a < N_ATOMS) atomicAdd(&c[classOf(x[(size_t)a * NFEAT])], 1);
  __syncthreads();
  if (threadIdx.x < 4) atomicAdd(&counters[threadIdx.x], c[threadIdx.x]);
}

// K2: exclusive scan of 4 counts -> cursors
__global__ void k_scan(int* __restrict__ counters)
{
  if (threadIdx.x == 0) {
    const int c0 = counters[0], c1 = counters[1], c2 = counters[2];
    counters[4] = 0;
    counters[5] = c0;
    counters[6] = c0 + c1;
    counters[7] = c0 + c1 + c2;
  }
}

// K3: scatter atom ids into class-sorted order[] (block-aggregated atomics)
__global__ __launch_bounds__(256) void k_scatter(const int* __restrict__ x,
    int* __restrict__ counters, int* __restrict__ order)
{
  __shared__ int cnt[4], base[4];
  if (threadIdx.x < 4) cnt[threadIdx.x] = 0;
  __syncthreads();
  const int a = blockIdx.x * 256 + threadIdx.x;
  int cl = 0, rank = 0;
  if (a < N_ATOMS) {
    cl = classOf(x[(size_t)a * NFEAT]);
    rank = atomicAdd(&cnt[cl], 1);
  }
  __syncthreads();
  if (threadIdx.x < 4) base[threadIdx.x] = atomicAdd(&counters[4 + threadIdx.x], cnt[threadIdx.x]);
  __syncthreads();
  if (a < N_ATOMS) order[base[cl] + rank] = a;
}

// K4: main — 64 atoms/block, 64-token chunks, BK=20 K-chunks in LDS,
//     4x4 register tile, fp32 top-2 + fp64 refinement, idx + loss partials.
__global__ __launch_bounds__(256) void k_main(
    const int* __restrict__ x, const float* __restrict__ e,
    const float* __restrict__ w, const int* __restrict__ order,
    const float* __restrict__ wnormf, const double* __restrict__ wnormd,
    int* __restrict__ idx, double* __restrict__ loss_part)
{
  __shared__ float4 et4[BM * BKSEG];   // [atom][5] float4  (5.1 KB)
  __shared__ float4 wt4[BN * BKSEG];   // [token][5] float4 (5.1 KB)
  __shared__ float4 red4[16 * 65];     // top-2 tuples      (16.6 KB)
  __shared__ int s_aid[BM], s_lo[BM], s_hi[BM], s_k1[BM], s_k2[BM];
  __shared__ int s_range[2];

  const int tid = threadIdx.x;

  if (tid < BM) {
    const int g = blockIdx.x * BM + tid;
    const int a = (g < N_ATOMS) ? order[g] : -1;
    s_aid[tid] = a;
    int lo = 1 << 30, hi = 0;
    if (a >= 0) classRange(x[(size_t)a * NFEAT], lo, hi);
    s_lo[tid] = lo; s_hi[tid] = hi;
    int kmn = lo, kmx = hi;
    #pragma unroll
    for (int off = 32; off; off >>= 1) {
      kmn = min(kmn, __shfl_down(kmn, off));
      kmx = max(kmx, __shfl_down(kmx, off));
    }
    if (tid == 0) { s_range[0] = kmn; s_range[1] = kmx; }
  }
  __syncthreads();

  const int kmin = s_range[0], kmax = s_range[1];
  const int tx = tid & 15, ty = tid >> 4;

  float m1[4], m2[4]; int k1[4], k2[4];
  #pragma unroll
  for (int i = 0; i < 4; i++) {
    m1[i] = __builtin_inff(); m2[i] = __builtin_inff();
    k1[i] = 0x7fffffff; k2[i] = 0x7fffffff;
  }

  for (int k0 = kmin; k0 < kmax; k0 += BN) {
    const int kn = min(BN, kmax - k0);
    float acc[4][4];
    #pragma unroll
    for (int i = 0; i < 4; i++) {
      #pragma unroll
      for (int j = 0; j < 4; j++) acc[i][j] = 0.f;
    }

    for (int kc = 0; kc < DIM; kc += BK) {
      // stage e chunk (zero-fill padding atoms)
      for (int s2 = tid; s2 < BM * BKSEG; s2 += 256) {
        const int r = s2 / BKSEG, c = s2 - r * BKSEG;
        const int a = s_aid[r];
        float4 v = make_float4(0.f, 0.f, 0.f, 0.f);
        if (a >= 0) v = *(const float4*)(e + (size_t)a * DIM + kc + 4 * c);
        et4[r * BKSEG + c] = v;
      }
      // stage w chunk
      for (int s2 = tid; s2 < kn * BKSEG; s2 += 256) {
        const int r = s2 / BKSEG, c = s2 - r * BKSEG;
        wt4[r * BKSEG + c] = *(const float4*)(w + (size_t)(k0 + r) * DIM + kc + 4 * c);
      }
      __syncthreads();

      #pragma unroll
      for (int c4 = 0; c4 < BKSEG; c4++) {
        float4 av[4], bv[4];
        #pragma unroll
        for (int i = 0; i < 4; i++) av[i] = et4[(tx + 16 * i) * BKSEG + c4];
        #pragma unroll
        for (int j = 0; j < 4; j++) bv[j] = wt4[(ty + 16 * j) * BKSEG + c4];
        #pragma unroll
        for (int i = 0; i < 4; i++) {
          #pragma unroll
          for (int j = 0; j < 4; j++) {
            acc[i][j] = fmaf(av[i].x, bv[j].x, acc[i][j]);
            acc[i][j] = fmaf(av[i].y, bv[j].y, acc[i][j]);
            acc[i][j] = fmaf(av[i].z, bv[j].z, acc[i][j]);
            acc[i][j] = fmaf(av[i].w, bv[j].w, acc[i][j]);
          }
        }
      }
      __syncthreads();
    }

    // top-2 update (ties -> lower k, scan order ascending)
    #pragma unroll
    for (int i = 0; i < 4; i++) {
      const int ai = tx + 16 * i;
      const int lo = s_lo[ai], hi = s_hi[ai];
      #pragma unroll
      for (int j = 0; j < 4; j++) {
        const int tloc = ty + 16 * j;
        const int k = k0 + tloc;
        if (tloc < kn && k >= lo && k < hi) {
          const float sc = wnormf[k] - 2.0f * acc[i][j];
          if (sc < m1[i]) { m2[i] = m1[i]; k2[i] = k1[i]; m1[i] = sc; k1[i] = k; }
          else if (sc < m2[i]) { m2[i] = sc; k2[i] = k; }
        }
      }
    }
  }

  // merge per-thread top-2 across the 16 token-threads of each atom
  #pragma unroll
  for (int i = 0; i < 4; i++) {
    const int ai = tx + 16 * i;
    red4[ty * 65 + ai] = make_float4(m1[i], __int_as_float(k1[i]),
                                     m2[i], __int_as_float(k2[i]));
  }
  __syncthreads();
  if (tid < BM) {
    float bm1 = __builtin_inff(), bm2 = __builtin_inff();
    int bk1 = 0x7fffffff, bk2 = 0x7fffffff;
    for (int t2 = 0; t2 < 16; t2++) {
      const float4 v = red4[t2 * 65 + tid];
      float n1 = v.x, n2 = v.z;
      int j1 = __float_as_int(v.y), j2 = __float_as_int(v.w);
      if (n1 < bm1 || (n1 == bm1 && j1 < bk1)) {
        const float tf = bm1; const int tk = bk1;
        bm1 = n1; bk1 = j1; n1 = tf; j1 = tk;
      }
      if (n1 < bm2 || (n1 == bm2 && j1 < bk2)) { bm2 = n1; bk2 = j1; }
      if (n2 < bm2 || (n2 == bm2 && j2 < bk2)) { bm2 = n2; bk2 = j2; }
    }
    s_k1[tid] = bk1; s_k2[tid] = bk2;
  }
  __syncthreads();

  // fp64 refinement of top-2, idx write + loss contribution
  const int wv = tid >> 6, lane = tid & 63;
  double wloss = 0.0;
  for (int a2 = wv * 16; a2 < wv * 16 + 16; a2++) {
    const int ag = s_aid[a2];
    if (ag < 0) continue;
    const int kk1 = s_k1[a2], kk2 = s_k2[a2];
    const float* erow = e + (size_t)ag * DIM;
    const float* w1 = w + (size_t)kk1 * DIM;
    const float* w2 = w + (size_t)kk2 * DIM;
    double d1 = 0.0, d2 = 0.0, en = 0.0;
    for (int d = lane; d < DIM; d += 64) {
      const double ev = (double)erow[d];
      en = fma(ev, ev, en);
      d1 = fma(ev, (double)w1[d], d1);
      d2 = fma(ev, (double)w2[d], d2);
    }
    #pragma unroll
    for (int off = 32; off; off >>= 1) {
      en += __shfl_down(en, off);
      d1 += __shfl_down(d1, off);
      d2 += __shfl_down(d2, off);
    }
    if (lane == 0) {
      const double s1 = wnormd[kk1] - 2.0 * d1;
      const double s2 = wnormd[kk2] - 2.0 * d2;
      int kb; double db;
      if (s2 < s1 || (s2 == s1 && kk2 < kk1)) { kb = kk2; db = s2; }
      else { kb = kk1; db = s1; }
      idx[ag] = kb;
      wloss += en + db;
    }
  }
  if (lane == 0) atomicAdd(&loss_part[blockIdx.x & 255], wloss);
}

// K5: gather quantized rows (float4, rows are 75 float4 so no straddle)
__global__ __launch_bounds__(256) void k_gather(const float* __restrict__ w,
    const int* __restrict__ idx, float* __restrict__ out)
{
  const int g = blockIdx.x * 256 + threadIdx.x;
  if (g >= N_ATOMS * NSEG4) return;
  const int atom = g / NSEG4;
  const int c = g - atom * NSEG4;
  const int k = idx[atom];
  ((float4*)out)[g] = *(const float4*)(w + (size_t)k * DIM + 4 * c);
}

// K6: reduce loss partials, write scalar
__global__ void k_final(const double* __restrict__ loss_part, float* __restrict__ out)
{
  __shared__ double sm[256];
  const int tid = threadIdx.x;
  sm[tid] = loss_part[tid];
  __syncthreads();
  for (int s = 128; s; s >>= 1) {
    if (tid < s) sm[tid] += sm[tid + s];
    __syncthreads();
  }
  if (tid == 0)
    out[(size_t)N_ATOMS * DIM] = (float)(1.25 * sm[0] / ((double)N_ATOMS * (double)DIM));
}

// Fallback (tiny ws): fused wave-per-atom, slow but correct.
__global__ __launch_bounds__(256) void k_fallback(
    const int* __restrict__ x, const float* __restrict__ e, const float* __restrict__ w,
    const float* __restrict__ wnormf, const double* __restrict__ wnormd,
    double* __restrict__ loss_part, float* __restrict__ out)
{
  const int wv = threadIdx.x >> 6, lane = threadIdx.x & 63;
  const int a = blockIdx.x * 4 + wv;
  if (a >= N_ATOMS) return;
  int lo, hi; classRange(x[(size_t)a * NFEAT], lo, hi);
  float er[5];
  #pragma unroll
  for (int j = 0; j < 5; j++) {
    const int d = j * 64 + lane;
    er[j] = (d < DIM) ? e[(size_t)a * DIM + d] : 0.f;
  }
  float m1 = __builtin_inff(), m2 = __builtin_inff();
  int k1 = 0x7fffffff, k2 = 0x7fffffff;
  const int iters = (hi - lo + 63) >> 6;
  for (int it = 0; it < iters; it++) {
    const int k = lo + it * 64 + lane;
    const bool val = (k < hi);
    const int ks = val ? k : lo;
    const float* wr = w + (size_t)ks * DIM;
    float acc = 0.f;
    #pragma unroll
    for (int j = 0; j < 5; j++) {
      const int dmax = min(64, DIM - j * 64);
      for (int dd = 0; dd < dmax; dd++)
        acc = fmaf(__shfl(er[j], dd), wr[j * 64 + dd], acc);
    }
    if (val) {
      const float sc = wnormf[k] - 2.0f * acc;
      if (sc < m1) { m2 = m1; k2 = k1; m1 = sc; k1 = k; }
      else if (sc < m2) { m2 = sc; k2 = k; }
    }
  }
  #pragma unroll
  for (int off = 32; off; off >>= 1) {
    float n1 = __shfl_xor(m1, off), n2 = __shfl_xor(m2, off);
    int j1 = __shfl_xor(k1, off), j2 = __shfl_xor(k2, off);
    if (n1 < m1 || (n1 == m1 && j1 < k1)) {
      const float tf = m1; const int tk = k1;
      m1 = n1; k1 = j1; n1 = tf; j1 = tk;
    }
    if (n1 < m2 || (n1 == m2 && j1 < k2)) { m2 = n1; k2 = j1; }
    if (n2 < m2 || (n2 == m2 && j2 < k2)) { m2 = n2; k2 = j2; }
  }
  double d1 = 0.0, d2 = 0.0, en = 0.0;
  const float* w1 = w + (size_t)k1 * DIM;
  const float* w2 = w + (size_t)k2 * DIM;
  for (int d = lane; d < DIM; d += 64) {
    const double ev = (double)e[(size_t)a * DIM + d];
    en = fma(ev, ev, en);
    d1 = fma(ev, (double)w1[d], d1);
    d2 = fma(ev, (double)w2[d], d2);
  }
  #pragma unroll
  for (int off = 32; off; off >>= 1) {
    en += __shfl_xor(en, off);
    d1 += __shfl_xor(d1, off);
    d2 += __shfl_xor(d2, off);
  }
  const double s1 = wnormd[k1] - 2.0 * d1;
  const double s2 = wnormd[k2] - 2.0 * d2;
  int kb; double db;
  if (s2 < s1 || (s2 == s1 && k2 < k1)) { kb = k2; db = s2; }
  else { kb = k1; db = s1; }
  #pragma unroll
  for (int j = 0; j < 5; j++) {
    const int d = j * 64 + lane;
    if (d < DIM) out[(size_t)a * DIM + d] = w[(size_t)kb * DIM + d];
  }
  if (lane == 0) atomicAdd(&loss_part[a & 255], en + db);
}

extern "C" void kernel_launch(void* const* d_in, const int* in_sizes, int n_in,
                              void* d_out, int out_size, void* d_ws, size_t ws_size,
                              hipStream_t stream)
{
  const int*   x = (const int*)d_in[0];
  const float* e = (const float*)d_in[1];
  const float* w = (const float*)d_in[2];
  float* out = (float*)d_out;
  char* ws = (char*)d_ws;

  double* loss_part = (double*)ws;                 // 256 doubles
  double* wnormd    = (double*)(ws + 2048);        // 512 doubles
  float*  wnormf    = (float*)(ws + 6144);         // 512 floats
  int*    counters  = (int*)(ws + 8192);           // 8 ints
  int*    order     = (int*)(ws + 8256);           // 500000 ints
  int*    idxb      = (int*)(ws + 2008256);        // 500000 ints

  k_prep<<<dim3(128), dim3(256), 0, stream>>>(w, wnormd, wnormf, loss_part, counters);

  if (ws_size >= (size_t)WS_FAST_NEED) {
    const int nb = (N_ATOMS + 255) / 256;          // 1954
    k_count<<<dim3(nb), dim3(256), 0, stream>>>(x, counters);
    k_scan<<<dim3(1), dim3(64), 0, stream>>>(counters);
    k_scatter<<<dim3(nb), dim3(256), 0, stream>>>(x, counters, order);
    k_main<<<dim3((N_ATOMS + BM - 1) / BM), dim3(256), 0, stream>>>(
        x, e, w, order, wnormf, wnormd, idxb, loss_part);
    k_gather<<<dim3((N_ATOMS * NSEG4 + 255) / 256), dim3(256), 0, stream>>>(w, idxb, out);
  } else {
    k_fallback<<<dim3((N_ATOMS + 3) / 4), dim3(256), 0, stream>>>(
        x, e, w, wnormf, wnormd, loss_part, out);
  }
  k_final<<<dim3(1), dim3(256), 0, stream>>>(loss_part, out);
}